// Round 3
// baseline (109.662 us; speedup 1.0000x reference)
//
#include <hip/hip_runtime.h>
#include <math.h>

#define NB 8
#define ND 128
#define NT 2048
#define NF 1025
#define NYY 256
#define NXX 256

#define SPEC_BYTES 8396800          /* 8*128*1025*8 */
#define BAND_PART_BYTES 2097152     /* 8*128*256*8 */

// workspace layout (bytes), chosen dynamically in kernel_launch:
//   [0..1024)        scale
//   [1024..4096)     part sums
//   SF_OFF   = 4096                 (sf: 8.4 MB; later reused as bandS)
//   SPECT_OFF= 4096+SPEC_BYTES      (specT: 8.4 MB; later overwritten by band)
//   band     = SPECT_OFF, FPART*2.1 MB
// need(FPART) = 4096 + SPEC_BYTES + FPART*BAND_PART_BYTES

// ---------------- kernel 1a: per-chunk sums for standardization ----------------
__global__ __launch_bounds__(256) void fk_part_sums(const float* __restrict__ sino,
                                                    double2* __restrict__ part) {
  const int c = blockIdx.x;   // 0..31 chunk
  const int b = blockIdx.y;   // 0..7 batch
  const int tid = threadIdx.x;
  const int chunk = ND * NT / 32;  // 8192
  const float* p = sino + (size_t)b * ND * NT + (size_t)c * chunk;
  double s = 0.0, ss = 0.0;
  for (int i = tid; i < chunk; i += 256) {
    float v = p[i];
    s += (double)v;
    ss += (double)v * (double)v;
  }
  __shared__ double shs[256];
  __shared__ double shq[256];
  shs[tid] = s; shq[tid] = ss;
  __syncthreads();
  for (int o = 128; o > 0; o >>= 1) {
    if (tid < o) { shs[tid] += shs[tid + o]; shq[tid] += shq[tid + o]; }
    __syncthreads();
  }
  if (tid == 0) part[b * 32 + c] = make_double2(shs[0], shq[0]);
}

// ---------------- kernel 1b: finalize 1/sqrt(var+eps) ----------------
__global__ void fk_scale_k(const double2* __restrict__ part, float* __restrict__ scale) {
  int t = threadIdx.x;
  if (t < NB) {
    double s = 0.0, ss = 0.0;
    for (int c = 0; c < 32; ++c) { double2 v = part[t * 32 + c]; s += v.x; ss += v.y; }
    const double n = (double)(ND * NT);
    double mean = s / n;
    double var = ss / n - mean * mean;
    scale[t] = (float)(1.0 / sqrt(var + 1.1920928955078125e-7));
  }
}

// ---------------- kernel 2: time FFT (2048-pt, Stockham radix-2) per (b,d) row ----------------
__global__ __launch_bounds__(256) void fk_tfft(const float* __restrict__ sino,
                                               float2* __restrict__ specT) {
  const int row = blockIdx.x;      // b*ND + d
  const int d = row & (ND - 1);
  const int tid = threadIdx.x;
  __shared__ float2 bufA[NT];
  __shared__ float2 bufB[NT];
  const float ap = (float)(0.5 - 0.5 * cos(6.283185307179586 * (double)d / 127.0));
  const float* in = sino + (size_t)row * NT;
  for (int i = tid; i < NT; i += 256) bufA[i] = make_float2(in[i] * ap, 0.0f);
  __syncthreads();
  float2* src = bufA;
  float2* dst = bufB;
  for (int p = 1; p <= NT / 2; p <<= 1) {
    for (int it = 0; it < NT / 2 / 256; ++it) {
      int i = tid + it * 256;
      int k = i & (p - 1);
      float2 u = src[i];
      float2 v = src[i + NT / 2];
      float ang = -3.14159265358979323846f * ((float)k / (float)p);
      float sn, cs; __sincosf(ang, &sn, &cs);
      float2 vw = make_float2(v.x * cs - v.y * sn, v.x * sn + v.y * cs);
      int j = ((i - k) << 1) + k;
      dst[j]     = make_float2(u.x + vw.x, u.y + vw.y);
      dst[j + p] = make_float2(u.x - vw.x, u.y - vw.y);
    }
    __syncthreads();
    float2* t = src; src = dst; dst = t;
  }
  float2* out = specT + (size_t)row * NF;
  for (int f = tid; f < NF; f += 256) out[f] = src[f];
}

// ---------------- kernel 3: detector FFT (128-pt) + prop_mask*fw ----------------
__global__ __launch_bounds__(256) void fk_dfft(const float2* __restrict__ specT,
                                               float2* __restrict__ sf) {
  const int b = blockIdx.y;
  const int f0 = blockIdx.x * 4;
  const int sub = threadIdx.x >> 6;   // 0..3 (which f)
  const int i = threadIdx.x & 63;     // butterfly index
  const int f = f0 + sub;
  const bool valid = (f < NF);
  __shared__ float2 A[4][128];
  __shared__ float2 Bf[4][128];
  if (valid) {
    const float2* col = specT + ((size_t)b * ND) * NF + f;
    A[sub][i]      = col[(size_t)i * NF];
    A[sub][i + 64] = col[(size_t)(i + 64) * NF];
  }
  __syncthreads();
  float2 (*src)[128] = A;
  float2 (*dst)[128] = Bf;
  for (int p = 1; p <= 64; p <<= 1) {
    if (valid) {
      int k = i & (p - 1);
      float2 u = src[sub][i];
      float2 v = src[sub][i + 64];
      float ang = -3.14159265358979323846f * ((float)k / (float)p);
      float sn, cs; __sincosf(ang, &sn, &cs);
      float2 vw = make_float2(v.x * cs - v.y * sn, v.x * sn + v.y * cs);
      int j = ((i - k) << 1) + k;
      dst[sub][j]     = make_float2(u.x + vw.x, u.y + vw.y);
      dst[sub][j + p] = make_float2(u.x - vw.x, u.y - vw.y);
    }
    __syncthreads();
    float2 (*t)[128] = src; src = dst; dst = t;
  }
  if (valid) {
    const float fwv = (f == 0 || f == NF - 1) ? 1.0f : 2.0f;
    double freqd = (double)f / 5.12e-5;
    float omega = (float)(freqd * 6.283185307179586);
    float woc = omega / 1540.0f;
    float woc2 = __fmul_rn(woc, woc);
    #pragma unroll
    for (int h = 0; h < 2; ++h) {
      int kd = i + h * 64;
      int kt = kd < 64 ? kd : kd - 128;
      float kxv = (float)(6.283185307179586 * ((double)kt / 0.0384));
      float kzsq = __fsub_rn(woc2, __fmul_rn(kxv, kxv));
      float m = (kzsq > 0.0f) ? fwv : 0.0f;
      float2 v = src[sub][kd];
      sf[((size_t)(b * ND + kd)) * NF + f] = make_float2(v.x * m, v.y * m);
    }
  }
}

// ---------------- kernel 4: band[part][b][d][y] = sum_f sf[b,d,f]*exp(i*kz*y) ----------------
// One block: one (d0, 128-d0) pair, ALL 8 batches, one f-part. 64 FMA per sincos.
__global__ __launch_bounds__(256, 4) void fk_band(const float2* __restrict__ sf,
                                                  float2* __restrict__ band,
                                                  int flen_base) {
  const int dg   = blockIdx.x;       // 0..64
  const int part = blockIdx.y;       // 0..FPART-1
  const int f0 = part * flen_base;
  const int flen = min(flen_base, NF - f0);
  const int tid = threadIdx.x;       // y
  const int d0 = dg;
  const int d1 = 128 - dg;
  const bool single = (dg == 0) || (dg == 64);

  extern __shared__ float lds[];
  float2* sfs = (float2*)lds;            // [flen_base][16]  (rows r = 2*b + dd)
  float*  kzs = lds + (size_t)flen_base * 32;

  #pragma unroll
  for (int r = 0; r < 16; ++r) {
    const int b = r >> 1, dd = r & 1;
    if (dd && single) {
      for (int ff = tid; ff < flen; ff += 256) sfs[ff * 16 + r] = make_float2(0.f, 0.f);
    } else {
      const int d = dd ? d1 : d0;
      const float2* src = sf + ((size_t)(b * ND + d)) * NF + f0;
      for (int ff = tid; ff < flen; ff += 256) sfs[ff * 16 + r] = src[ff];
    }
  }
  {
    float kxv = (float)(6.283185307179586 * ((double)d0 / 0.0384));
    float kx2 = __fmul_rn(kxv, kxv);
    for (int ff = tid; ff < flen; ff += 256) {
      int f = f0 + ff;
      double freqd = (double)f / 5.12e-5;
      float omega = (float)(freqd * 6.283185307179586);
      float woc = omega / 1540.0f;
      float kzsq = __fsub_rn(__fmul_rn(woc, woc), kx2);
      kzs[ff] = (kzsq > 0.0f) ? sqrtf(kzsq) : 0.0f;
    }
  }
  __syncthreads();

  const float yv = (float)(1.0e-3 + (double)tid * 1.5e-4);
  float2 acc[16];
  #pragma unroll
  for (int r = 0; r < 16; ++r) acc[r] = make_float2(0.f, 0.f);

  const float4* sfs4 = (const float4*)sfs;
  for (int ff = 0; ff < flen; ++ff) {
    float ang = kzs[ff] * yv;
    float sn, cs; __sincosf(ang, &sn, &cs);
    #pragma unroll
    for (int j = 0; j < 8; ++j) {
      float4 p = sfs4[ff * 8 + j];       // rows 2j, 2j+1 — wave-uniform broadcast
      acc[2*j].x   = fmaf(p.x, cs, fmaf(-p.y, sn, acc[2*j].x));
      acc[2*j].y   = fmaf(p.x, sn, fmaf( p.y, cs, acc[2*j].y));
      acc[2*j+1].x = fmaf(p.z, cs, fmaf(-p.w, sn, acc[2*j+1].x));
      acc[2*j+1].y = fmaf(p.z, sn, fmaf( p.w, cs, acc[2*j+1].y));
    }
  }

  #pragma unroll
  for (int r = 0; r < 16; ++r) {
    const int b = r >> 1, dd = r & 1;
    if (dd && single) continue;
    const int d = dd ? d1 : d0;
    band[(((size_t)(part * NB + b)) * ND + d) * NYY + tid] = acc[r];  // coalesced (lane=y)
  }
}

// ---------------- kernel 4b: bandS[b][y][d] = sum_part band[part][b][d][y] ----------------
__global__ __launch_bounds__(256) void fk_sum(const float2* __restrict__ band,
                                              float2* __restrict__ bandS, int nparts) {
  const int n = blockIdx.x * 256 + threadIdx.x;   // over b*ND*NYY, coalesced read
  const int y = n & 255;
  const int d = (n >> 8) & 127;
  const int b = n >> 15;
  float2 s = make_float2(0.f, 0.f);
  for (int p = 0; p < nparts; ++p) {
    float2 v = band[(size_t)p * (NB * ND * NYY) + n];
    s.x += v.x; s.y += v.y;
  }
  bandS[((size_t)b * NYY + y) * ND + d] = s;
}

// ---------------- kernel 5: lateral inverse DFT + magnitude ----------------
__global__ __launch_bounds__(256) void fk_img(const float2* __restrict__ bandS,
                                              const float* __restrict__ scale,
                                              float* __restrict__ out, float inv_norm) {
  const int y = blockIdx.x;
  const int b = blockIdx.y;
  const int tid = threadIdx.x;
  __shared__ float2 bs[ND];
  if (tid < ND) bs[tid] = bandS[((size_t)b * NYY + y) * ND + tid];  // coalesced
  __syncthreads();
  const int x = tid;
  float ang = (float)(6.283185307179586 * (double)x / 256.0);
  float sn, cs; __sincosf(ang, &sn, &cs);
  const float2 step = make_float2(cs, sn);
  float2 w = make_float2(1.0f, 0.0f);
  float2 acc = make_float2(0.0f, 0.0f);
  #pragma unroll 4
  for (int d = 0; d < 64; ++d) {
    float2 v = bs[d];
    acc.x = fmaf(v.x, w.x, fmaf(-v.y, w.y, acc.x));
    acc.y = fmaf(v.x, w.y, fmaf( v.y, w.x, acc.y));
    float2 nw;
    nw.x = fmaf(w.x, step.x, -w.y * step.y);
    nw.y = fmaf(w.x, step.y,  w.y * step.x);
    w = nw;
  }
  if (x & 1) { w.x = -w.x; w.y = -w.y; }   // step^128 = (-1)^x at the d=64 wrap
  #pragma unroll 4
  for (int d = 64; d < 128; ++d) {
    float2 v = bs[d];
    acc.x = fmaf(v.x, w.x, fmaf(-v.y, w.y, acc.x));
    acc.y = fmaf(v.x, w.y, fmaf( v.y, w.x, acc.y));
    float2 nw;
    nw.x = fmaf(w.x, step.x, -w.y * step.y);
    nw.y = fmaf(w.x, step.y,  w.y * step.x);
    w = nw;
  }
  float mag = sqrtf(acc.x * acc.x + acc.y * acc.y);
  out[((size_t)b * NYY + y) * NXX + x] = mag * scale[b] * inv_norm;
}

extern "C" void kernel_launch(void* const* d_in, const int* in_sizes, int n_in,
                              void* d_out, int out_size, void* d_ws, size_t ws_size,
                              hipStream_t stream) {
  const float* sino = (const float*)d_in[0];
  float* out = (float*)d_out;
  char* ws = (char*)d_ws;

  float*   scale = (float*)(ws + 0);
  double2* part  = (double2*)(ws + 1024);
  float2*  sf    = (float2*)(ws + 4096);
  float2*  specT = (float2*)(ws + 4096 + SPEC_BYTES);
  float2*  band  = specT;                 // overwrites specT (dead after fk_dfft)
  float2*  bandS = sf;                    // overwrites sf (dead after fk_band)

  // pick f-partition count from available workspace (deterministic given ws_size)
  int FPART = 4;
  if (ws_size >= (size_t)4096 + SPEC_BYTES + 16u * BAND_PART_BYTES) FPART = 16;
  else if (ws_size >= (size_t)4096 + SPEC_BYTES + 8u * BAND_PART_BYTES) FPART = 8;
  const int flen_base = (NF + FPART - 1) / FPART;          // 65 / 129 / 257
  const size_t band_lds = (size_t)flen_base * 132;         // 16 float2 + 1 float per ff

  double apod_sum = 0.0;
  for (int n = 0; n < ND; ++n) apod_sum += 0.5 - 0.5 * cos(6.283185307179586 * (double)n / 127.0);
  const float inv_norm = (float)(1.0 / (apod_sum * 2048.0));

  fk_part_sums<<<dim3(32, NB), 256, 0, stream>>>(sino, part);
  fk_scale_k <<<1, 64, 0, stream>>>(part, scale);
  fk_tfft    <<<NB * ND, 256, 0, stream>>>(sino, specT);
  fk_dfft    <<<dim3((NF + 3) / 4, NB), 256, 0, stream>>>(specT, sf);
  fk_band    <<<dim3(65, FPART), 256, band_lds, stream>>>(sf, band, flen_base);
  fk_sum     <<<NB * ND * NYY / 256, 256, 0, stream>>>(band, bandS, FPART);
  fk_img     <<<dim3(NYY, NB), 256, 0, stream>>>(bandS, scale, out, inv_norm);
}

// Round 5
// 103.763 us; speedup vs baseline: 1.0569x; 1.0569x over previous
//
#include <hip/hip_runtime.h>
#include <math.h>

#define NB 8
#define ND 128
#define NT 2048
#define NF 1025
#define NYY 256
#define NXX 256

#define SPEC_BYTES 8396800          /* 8*128*1025*8 */
#define BAND_PART_BYTES 2097152     /* 8*128*256*8 */

// workspace layout (bytes), chosen dynamically in kernel_launch:
//   [0..1024)        scale
//   [1024..4096)     part sums
//   SF_OFF   = 4096                 (sf: 8.4 MB; later reused as bandS)
//   SPECT_OFF= 4096+SPEC_BYTES      (specT: 8.4 MB; later overwritten by band)
//   band     = SPECT_OFF, FPART*2.1 MB
// need(FPART) = 4096 + SPEC_BYTES + FPART*BAND_PART_BYTES

// ---------------- kernel 1a: per-chunk sums for standardization ----------------
__global__ __launch_bounds__(256) void fk_part_sums(const float* __restrict__ sino,
                                                    double2* __restrict__ part) {
  const int c = blockIdx.x;   // 0..31 chunk
  const int b = blockIdx.y;   // 0..7 batch
  const int tid = threadIdx.x;
  const int chunk = ND * NT / 32;  // 8192
  const float* p = sino + (size_t)b * ND * NT + (size_t)c * chunk;
  double s = 0.0, ss = 0.0;
  for (int i = tid; i < chunk; i += 256) {
    float v = p[i];
    s += (double)v;
    ss += (double)v * (double)v;
  }
  __shared__ double shs[256];
  __shared__ double shq[256];
  shs[tid] = s; shq[tid] = ss;
  __syncthreads();
  for (int o = 128; o > 0; o >>= 1) {
    if (tid < o) { shs[tid] += shs[tid + o]; shq[tid] += shq[tid + o]; }
    __syncthreads();
  }
  if (tid == 0) part[b * 32 + c] = make_double2(shs[0], shq[0]);
}

// ---------------- kernel 1b: finalize 1/sqrt(var+eps) ----------------
__global__ void fk_scale_k(const double2* __restrict__ part, float* __restrict__ scale) {
  int t = threadIdx.x;
  if (t < NB) {
    double s = 0.0, ss = 0.0;
    for (int c = 0; c < 32; ++c) { double2 v = part[t * 32 + c]; s += v.x; ss += v.y; }
    const double n = (double)(ND * NT);
    double mean = s / n;
    double var = ss / n - mean * mean;
    scale[t] = (float)(1.0 / sqrt(var + 1.1920928955078125e-7));
  }
}

// ---------------- kernel 2: real 2048-pt rfft via 1024-pt complex FFT + untangle ----
__global__ __launch_bounds__(256) void fk_tfft(const float* __restrict__ sino,
                                               float2* __restrict__ specT) {
  const int row = blockIdx.x;      // b*ND + d
  const int d = row & (ND - 1);
  const int tid = threadIdx.x;
  __shared__ float2 bufA[1024];
  __shared__ float2 bufB[1024];
  const float ap = (float)(0.5 - 0.5 * cos(6.283185307179586 * (double)d / 127.0));
  const float2* in = (const float2*)(sino + (size_t)row * NT);   // z[n] = x[2n] + i x[2n+1]
  for (int i = tid; i < 1024; i += 256) {
    float2 v = in[i];
    bufA[i] = make_float2(v.x * ap, v.y * ap);
  }
  __syncthreads();
  float2* src = bufA;
  float2* dst = bufB;
  for (int p = 1; p <= 512; p <<= 1) {
    #pragma unroll
    for (int it = 0; it < 2; ++it) {
      int i = tid + it * 256;
      int k = i & (p - 1);
      float2 u = src[i];
      float2 v = src[i + 512];
      float ang = -3.14159265358979323846f * ((float)k / (float)p);
      float sn, cs; __sincosf(ang, &sn, &cs);
      float2 vw = make_float2(v.x * cs - v.y * sn, v.x * sn + v.y * cs);
      int j = ((i - k) << 1) + k;
      dst[j]     = make_float2(u.x + vw.x, u.y + vw.y);
      dst[j + p] = make_float2(u.x - vw.x, u.y - vw.y);
    }
    __syncthreads();
    float2* t = src; src = dst; dst = t;
  }
  // src = Z[0..1023]; untangle to rfft X[0..1024]
  float2* out = specT + (size_t)row * NF;
  for (int k = tid; k < 1024; k += 256) {
    float2 zk = src[k];
    float2 zc = src[(1024 - k) & 1023]; zc.y = -zc.y;          // conj
    float2 xe = make_float2(0.5f * (zk.x + zc.x), 0.5f * (zk.y + zc.y));
    float ax = zk.x - zc.x, ay = zk.y - zc.y;
    float2 xo = make_float2(0.5f * ay, -0.5f * ax);            // (Z - Zc)/(2i)
    float ang = -3.14159265358979323846f * ((float)k / 1024.0f);
    float sn, cs; __sincosf(ang, &sn, &cs);
    out[k] = make_float2(xe.x + cs * xo.x - sn * xo.y,
                         xe.y + cs * xo.y + sn * xo.x);
  }
  if (tid == 0) {
    float2 z0 = src[0];
    out[1024] = make_float2(z0.x - z0.y, 0.0f);
  }
}

// ---------------- kernel 3: detector FFT (128-pt) + prop_mask*fw ----------------
__global__ __launch_bounds__(256) void fk_dfft(const float2* __restrict__ specT,
                                               float2* __restrict__ sf) {
  const int b = blockIdx.y;
  const int f0 = blockIdx.x * 4;
  const int sub = threadIdx.x >> 6;   // 0..3 (which f)
  const int i = threadIdx.x & 63;     // butterfly index
  const int f = f0 + sub;
  const bool valid = (f < NF);
  __shared__ float2 A[4][128];
  __shared__ float2 Bf[4][128];
  if (valid) {
    const float2* col = specT + ((size_t)b * ND) * NF + f;
    A[sub][i]      = col[(size_t)i * NF];
    A[sub][i + 64] = col[(size_t)(i + 64) * NF];
  }
  __syncthreads();
  float2 (*src)[128] = A;
  float2 (*dst)[128] = Bf;
  for (int p = 1; p <= 64; p <<= 1) {
    if (valid) {
      int k = i & (p - 1);
      float2 u = src[sub][i];
      float2 v = src[sub][i + 64];
      float ang = -3.14159265358979323846f * ((float)k / (float)p);
      float sn, cs; __sincosf(ang, &sn, &cs);
      float2 vw = make_float2(v.x * cs - v.y * sn, v.x * sn + v.y * cs);
      int j = ((i - k) << 1) + k;
      dst[sub][j]     = make_float2(u.x + vw.x, u.y + vw.y);
      dst[sub][j + p] = make_float2(u.x - vw.x, u.y - vw.y);
    }
    __syncthreads();
    float2 (*t)[128] = src; src = dst; dst = t;
  }
  if (valid) {
    const float fwv = (f == 0 || f == NF - 1) ? 1.0f : 2.0f;
    double freqd = (double)f / 5.12e-5;
    float omega = (float)(freqd * 6.283185307179586);
    float woc = omega / 1540.0f;
    float woc2 = __fmul_rn(woc, woc);
    #pragma unroll
    for (int h = 0; h < 2; ++h) {
      int kd = i + h * 64;
      int kt = kd < 64 ? kd : kd - 128;
      float kxv = (float)(6.283185307179586 * ((double)kt / 0.0384));
      float kzsq = __fsub_rn(woc2, __fmul_rn(kxv, kxv));
      float m = (kzsq > 0.0f) ? fwv : 0.0f;
      float2 v = src[sub][kd];
      sf[((size_t)(b * ND + kd)) * NF + f] = make_float2(v.x * m, v.y * m);
    }
  }
}

// ---------------- kernel 4: band[part][b][d][y] = sum_f sf[b,d,f]*exp(i*kz*y) ----------------
// One block: one (d0, 128-d0) pair, ALL 8 batches, one f-part. 64 FMA per sincos.
__global__ __launch_bounds__(256) void fk_band(const float2* __restrict__ sf,
                                               float2* __restrict__ band,
                                               int flen_base) {
  const int dg   = blockIdx.x;       // 0..64
  const int part = blockIdx.y;       // 0..FPART-1
  const int f0 = part * flen_base;
  const int flen = min(flen_base, NF - f0);
  const int tid = threadIdx.x;       // y
  const int d0 = dg;
  const int d1 = 128 - dg;
  const bool single = (dg == 0) || (dg == 64);

  extern __shared__ float lds[];
  float2* sfs = (float2*)lds;            // [flen_base][16]  (rows r = 2*b + dd)
  float*  kzs = lds + (size_t)flen_base * 32;

  #pragma unroll
  for (int r = 0; r < 16; ++r) {
    const int b = r >> 1, dd = r & 1;
    if (dd && single) {
      for (int ff = tid; ff < flen; ff += 256) sfs[ff * 16 + r] = make_float2(0.f, 0.f);
    } else {
      const int d = dd ? d1 : d0;
      const float2* src = sf + ((size_t)(b * ND + d)) * NF + f0;
      for (int ff = tid; ff < flen; ff += 256) sfs[ff * 16 + r] = src[ff];
    }
  }
  {
    float kxv = (float)(6.283185307179586 * ((double)d0 / 0.0384));
    float kx2 = __fmul_rn(kxv, kxv);
    for (int ff = tid; ff < flen; ff += 256) {
      int f = f0 + ff;
      double freqd = (double)f / 5.12e-5;
      float omega = (float)(freqd * 6.283185307179586);
      float woc = omega / 1540.0f;
      float kzsq = __fsub_rn(__fmul_rn(woc, woc), kx2);
      kzs[ff] = (kzsq > 0.0f) ? sqrtf(kzsq) : 0.0f;
    }
  }
  __syncthreads();

  const float yv = (float)(1.0e-3 + (double)tid * 1.5e-4);
  float2 acc[16];
  #pragma unroll
  for (int r = 0; r < 16; ++r) acc[r] = make_float2(0.f, 0.f);

  const float4* sfs4 = (const float4*)sfs;
  for (int ff = 0; ff < flen; ++ff) {
    float ang = kzs[ff] * yv;
    float sn, cs; __sincosf(ang, &sn, &cs);
    #pragma unroll
    for (int j = 0; j < 8; ++j) {
      float4 p = sfs4[ff * 8 + j];       // rows 2j, 2j+1 — wave-uniform broadcast
      acc[2*j].x   = fmaf(p.x, cs, fmaf(-p.y, sn, acc[2*j].x));
      acc[2*j].y   = fmaf(p.x, sn, fmaf( p.y, cs, acc[2*j].y));
      acc[2*j+1].x = fmaf(p.z, cs, fmaf(-p.w, sn, acc[2*j+1].x));
      acc[2*j+1].y = fmaf(p.z, sn, fmaf( p.w, cs, acc[2*j+1].y));
    }
  }

  #pragma unroll
  for (int r = 0; r < 16; ++r) {
    const int b = r >> 1, dd = r & 1;
    if (dd && single) continue;
    const int d = dd ? d1 : d0;
    band[(((size_t)(part * NB + b)) * ND + d) * NYY + tid] = acc[r];  // coalesced (lane=y)
  }
}

// ---------------- kernel 4b: bandS[b][y][d] = sum_part band[part][b][d][y] ----------------
__global__ __launch_bounds__(256) void fk_sum(const float2* __restrict__ band,
                                              float2* __restrict__ bandS, int nparts) {
  const int n = blockIdx.x * 256 + threadIdx.x;   // over b*ND*NYY, coalesced read
  const int y = n & 255;
  const int d = (n >> 8) & 127;
  const int b = n >> 15;
  float2 s = make_float2(0.f, 0.f);
  for (int p = 0; p < nparts; ++p) {
    float2 v = band[(size_t)p * (NB * ND * NYY) + n];
    s.x += v.x; s.y += v.y;
  }
  bandS[((size_t)b * NYY + y) * ND + d] = s;
}

// ---------------- kernel 5: lateral inverse DFT + magnitude ----------------
__global__ __launch_bounds__(256) void fk_img(const float2* __restrict__ bandS,
                                              const float* __restrict__ scale,
                                              float* __restrict__ out, float inv_norm) {
  const int y = blockIdx.x;
  const int b = blockIdx.y;
  const int tid = threadIdx.x;
  __shared__ float2 bs[ND];
  if (tid < ND) bs[tid] = bandS[((size_t)b * NYY + y) * ND + tid];  // coalesced
  __syncthreads();
  const int x = tid;
  float ang = (float)(6.283185307179586 * (double)x / 256.0);
  float sn, cs; __sincosf(ang, &sn, &cs);
  const float2 step = make_float2(cs, sn);
  float2 w = make_float2(1.0f, 0.0f);
  float2 acc = make_float2(0.0f, 0.0f);
  #pragma unroll 4
  for (int d = 0; d < 64; ++d) {
    float2 v = bs[d];
    acc.x = fmaf(v.x, w.x, fmaf(-v.y, w.y, acc.x));
    acc.y = fmaf(v.x, w.y, fmaf( v.y, w.x, acc.y));
    float2 nw;
    nw.x = fmaf(w.x, step.x, -w.y * step.y);
    nw.y = fmaf(w.x, step.y,  w.y * step.x);
    w = nw;
  }
  if (x & 1) { w.x = -w.x; w.y = -w.y; }   // step^128 = (-1)^x at the d=64 wrap
  #pragma unroll 4
  for (int d = 64; d < 128; ++d) {
    float2 v = bs[d];
    acc.x = fmaf(v.x, w.x, fmaf(-v.y, w.y, acc.x));
    acc.y = fmaf(v.x, w.y, fmaf( v.y, w.x, acc.y));
    float2 nw;
    nw.x = fmaf(w.x, step.x, -w.y * step.y);
    nw.y = fmaf(w.x, step.y,  w.y * step.x);
    w = nw;
  }
  float mag = sqrtf(acc.x * acc.x + acc.y * acc.y);
  out[((size_t)b * NYY + y) * NXX + x] = mag * scale[b] * inv_norm;
}

extern "C" void kernel_launch(void* const* d_in, const int* in_sizes, int n_in,
                              void* d_out, int out_size, void* d_ws, size_t ws_size,
                              hipStream_t stream) {
  const float* sino = (const float*)d_in[0];
  float* out = (float*)d_out;
  char* ws = (char*)d_ws;

  float*   scale = (float*)(ws + 0);
  double2* part  = (double2*)(ws + 1024);
  float2*  sf    = (float2*)(ws + 4096);
  float2*  specT = (float2*)(ws + 4096 + SPEC_BYTES);
  float2*  band  = specT;                 // overwrites specT (dead after fk_dfft)
  float2*  bandS = sf;                    // overwrites sf (dead after fk_band)

  // pick f-partition count from available workspace (deterministic given ws_size)
  int FPART = 4;
  if (ws_size >= (size_t)4096 + SPEC_BYTES + 16u * BAND_PART_BYTES) FPART = 16;
  else if (ws_size >= (size_t)4096 + SPEC_BYTES + 8u * BAND_PART_BYTES) FPART = 8;
  const int flen_base = (NF + FPART - 1) / FPART;          // 65 / 129 / 257
  const size_t band_lds = (size_t)flen_base * 132;         // 16 float2 + 1 float per ff

  double apod_sum = 0.0;
  for (int n = 0; n < ND; ++n) apod_sum += 0.5 - 0.5 * cos(6.283185307179586 * (double)n / 127.0);
  const float inv_norm = (float)(1.0 / (apod_sum * 2048.0));

  fk_part_sums<<<dim3(32, NB), 256, 0, stream>>>(sino, part);
  fk_scale_k <<<1, 64, 0, stream>>>(part, scale);
  fk_tfft    <<<NB * ND, 256, 0, stream>>>(sino, specT);
  fk_dfft    <<<dim3((NF + 3) / 4, NB), 256, 0, stream>>>(specT, sf);
  fk_band    <<<dim3(65, FPART), 256, band_lds, stream>>>(sf, band, flen_base);
  fk_sum     <<<NB * ND * NYY / 256, 256, 0, stream>>>(band, bandS, FPART);
  fk_img     <<<dim3(NYY, NB), 256, 0, stream>>>(bandS, scale, out, inv_norm);
}

// Round 6
// 92.455 us; speedup vs baseline: 1.1861x; 1.1223x over previous
//
#include <hip/hip_runtime.h>
#include <math.h>

#define NB 8
#define ND 128
#define NT 2048
#define NF 1025
#define NYY 256
#define NXX 256

#define SPEC_BYTES 8396800          /* 8*128*1025*8 */
#define BAND_PART_BYTES 2097152     /* 8*128*256*8 */
#define PART_OFF   1024
#define SPECT_OFF  8192
#define SF_OFF     (SPECT_OFF + SPEC_BYTES)            /* 8,404,992 */
#define BAND_OFF   (SF_OFF + SPEC_BYTES)               /* 16,801,792 */
// bandS goes after band (FPART * BAND_PART_BYTES). No aliasing at all.

// ---------------- kernel 1a: per-chunk sums for standardization ----------------
__global__ __launch_bounds__(256) void fk_part_sums(const float* __restrict__ sino,
                                                    double2* __restrict__ part) {
  const int c = blockIdx.x;   // 0..31 chunk
  const int b = blockIdx.y;   // 0..7 batch
  const int tid = threadIdx.x;
  const int chunk = ND * NT / 32;  // 8192
  const float* p = sino + (size_t)b * ND * NT + (size_t)c * chunk;
  double s = 0.0, ss = 0.0;
  for (int i = tid; i < chunk; i += 256) {
    float v = p[i];
    s += (double)v;
    ss += (double)v * (double)v;
  }
  __shared__ double shs[256];
  __shared__ double shq[256];
  shs[tid] = s; shq[tid] = ss;
  __syncthreads();
  for (int o = 128; o > 0; o >>= 1) {
    if (tid < o) { shs[tid] += shs[tid + o]; shq[tid] += shq[tid + o]; }
    __syncthreads();
  }
  if (tid == 0) part[b * 32 + c] = make_double2(shs[0], shq[0]);
}

// ---------------- kernel 1b: finalize 1/sqrt(var+eps) ----------------
__global__ void fk_scale_k(const double2* __restrict__ part, float* __restrict__ scale) {
  int t = threadIdx.x;
  if (t < NB) {
    double s = 0.0, ss = 0.0;
    for (int c = 0; c < 32; ++c) { double2 v = part[t * 32 + c]; s += v.x; ss += v.y; }
    const double n = (double)(ND * NT);
    double mean = s / n;
    double var = ss / n - mean * mean;
    scale[t] = (float)(1.0 / sqrt(var + 1.1920928955078125e-7));
  }
}

// ---------------- kernel 2: real 2048-pt rfft via 1024-pt complex FFT + untangle ----
__global__ __launch_bounds__(256) void fk_tfft(const float* __restrict__ sino,
                                               float2* __restrict__ specT) {
  const int row = blockIdx.x;      // b*ND + d
  const int d = row & (ND - 1);
  const int tid = threadIdx.x;
  __shared__ float2 bufA[1024];
  __shared__ float2 bufB[1024];
  const float ap = (float)(0.5 - 0.5 * cos(6.283185307179586 * (double)d / 127.0));
  const float2* in = (const float2*)(sino + (size_t)row * NT);   // z[n] = x[2n] + i x[2n+1]
  for (int i = tid; i < 1024; i += 256) {
    float2 v = in[i];
    bufA[i] = make_float2(v.x * ap, v.y * ap);
  }
  __syncthreads();
  float2* src = bufA;
  float2* dst = bufB;
  for (int p = 1; p <= 512; p <<= 1) {
    #pragma unroll
    for (int it = 0; it < 2; ++it) {
      int i = tid + it * 256;
      int k = i & (p - 1);
      float2 u = src[i];
      float2 v = src[i + 512];
      float ang = -3.14159265358979323846f * ((float)k / (float)p);
      float sn, cs; __sincosf(ang, &sn, &cs);
      float2 vw = make_float2(v.x * cs - v.y * sn, v.x * sn + v.y * cs);
      int j = ((i - k) << 1) + k;
      dst[j]     = make_float2(u.x + vw.x, u.y + vw.y);
      dst[j + p] = make_float2(u.x - vw.x, u.y - vw.y);
    }
    __syncthreads();
    float2* t = src; src = dst; dst = t;
  }
  // src = Z[0..1023]; untangle to rfft X[0..1024]
  float2* out = specT + (size_t)row * NF;
  for (int k = tid; k < 1024; k += 256) {
    float2 zk = src[k];
    float2 zc = src[(1024 - k) & 1023]; zc.y = -zc.y;          // conj
    float2 xe = make_float2(0.5f * (zk.x + zc.x), 0.5f * (zk.y + zc.y));
    float ax = zk.x - zc.x, ay = zk.y - zc.y;
    float2 xo = make_float2(0.5f * ay, -0.5f * ax);            // (Z - Zc)/(2i)
    float ang = -3.14159265358979323846f * ((float)k / 1024.0f);
    float sn, cs; __sincosf(ang, &sn, &cs);
    out[k] = make_float2(xe.x + cs * xo.x - sn * xo.y,
                         xe.y + cs * xo.y + sn * xo.x);
  }
  if (tid == 0) {
    float2 z0 = src[0];
    out[1024] = make_float2(z0.x - z0.y, 0.0f);
  }
}

// ---------------- kernel 3: detector FFT (128-pt) + prop_mask*fw ----------------
__global__ __launch_bounds__(256) void fk_dfft(const float2* __restrict__ specT,
                                               float2* __restrict__ sf) {
  const int b = blockIdx.y;
  const int f0 = blockIdx.x * 4;
  const int sub = threadIdx.x >> 6;   // 0..3 (which f)
  const int i = threadIdx.x & 63;     // butterfly index
  const int f = f0 + sub;
  const bool valid = (f < NF);
  __shared__ float2 A[4][128];
  __shared__ float2 Bf[4][128];
  if (valid) {
    const float2* col = specT + ((size_t)b * ND) * NF + f;
    A[sub][i]      = col[(size_t)i * NF];
    A[sub][i + 64] = col[(size_t)(i + 64) * NF];
  }
  __syncthreads();
  float2 (*src)[128] = A;
  float2 (*dst)[128] = Bf;
  for (int p = 1; p <= 64; p <<= 1) {
    if (valid) {
      int k = i & (p - 1);
      float2 u = src[sub][i];
      float2 v = src[sub][i + 64];
      float ang = -3.14159265358979323846f * ((float)k / (float)p);
      float sn, cs; __sincosf(ang, &sn, &cs);
      float2 vw = make_float2(v.x * cs - v.y * sn, v.x * sn + v.y * cs);
      int j = ((i - k) << 1) + k;
      dst[sub][j]     = make_float2(u.x + vw.x, u.y + vw.y);
      dst[sub][j + p] = make_float2(u.x - vw.x, u.y - vw.y);
    }
    __syncthreads();
    float2 (*t)[128] = src; src = dst; dst = t;
  }
  if (valid) {
    const float fwv = (f == 0 || f == NF - 1) ? 1.0f : 2.0f;
    double freqd = (double)f / 5.12e-5;
    float omega = (float)(freqd * 6.283185307179586);
    float woc = omega / 1540.0f;
    float woc2 = __fmul_rn(woc, woc);
    #pragma unroll
    for (int h = 0; h < 2; ++h) {
      int kd = i + h * 64;
      int kt = kd < 64 ? kd : kd - 128;
      float kxv = (float)(6.283185307179586 * ((double)kt / 0.0384));
      float kzsq = __fsub_rn(woc2, __fmul_rn(kxv, kxv));
      float m = (kzsq > 0.0f) ? fwv : 0.0f;
      float2 v = src[sub][kd];
      sf[((size_t)(b * ND + kd)) * NF + f] = make_float2(v.x * m, v.y * m);
    }
  }
}

// ---------------- kernel 4: band[part][b][d][y] = sum_f sf[b,d,f]*exp(i*kz*y) ----------------
// sf reads are block-uniform -> scalar loads; no LDS staging of sf at all.
__global__ __launch_bounds__(256) void fk_band(const float2* __restrict__ sf,
                                               float2* __restrict__ band,
                                               int flen_base) {
  const int dg   = blockIdx.x;       // 0..64
  const int part = blockIdx.y;       // 0..FPART-1
  const int f0 = part * flen_base;
  const int flen = min(flen_base, NF - f0);
  const int tid = threadIdx.x;       // y
  const int d0 = dg;
  const bool single = (dg == 0) || (dg == 64);
  const int d1 = single ? dg : (ND - dg);    // always a valid row

  __shared__ float kzs[257];
  {
    float kxv = (float)(6.283185307179586 * ((double)d0 / 0.0384));
    float kx2 = __fmul_rn(kxv, kxv);
    for (int ff = tid; ff < flen; ff += 256) {
      int f = f0 + ff;
      double freqd = (double)f / 5.12e-5;
      float omega = (float)(freqd * 6.283185307179586);
      float woc = omega / 1540.0f;
      float kzsq = __fsub_rn(__fmul_rn(woc, woc), kx2);
      kzs[ff] = (kzsq > 0.0f) ? sqrtf(kzsq) : 0.0f;
    }
  }
  __syncthreads();

  const float yv = (float)(1.0e-3 + (double)tid * 1.5e-4);
  float2 acc[16];
  #pragma unroll
  for (int r = 0; r < 16; ++r) acc[r] = make_float2(0.f, 0.f);

  const float2* baseA = sf + (size_t)d0 * NF + f0;   // + b*ND*NF + ff
  const float2* baseB = sf + (size_t)d1 * NF + f0;
  const size_t bstr = (size_t)ND * NF;

  for (int ff = 0; ff < flen; ++ff) {
    float ang = kzs[ff] * yv;
    float sn, cs; __sincosf(ang, &sn, &cs);
    #pragma unroll
    for (int b = 0; b < NB; ++b) {
      float2 pa = baseA[(size_t)b * bstr + ff];   // block-uniform -> s_load
      float2 pb = baseB[(size_t)b * bstr + ff];
      acc[2*b].x   = fmaf(pa.x, cs, fmaf(-pa.y, sn, acc[2*b].x));
      acc[2*b].y   = fmaf(pa.x, sn, fmaf( pa.y, cs, acc[2*b].y));
      acc[2*b+1].x = fmaf(pb.x, cs, fmaf(-pb.y, sn, acc[2*b+1].x));
      acc[2*b+1].y = fmaf(pb.x, sn, fmaf( pb.y, cs, acc[2*b+1].y));
    }
  }

  #pragma unroll
  for (int b = 0; b < NB; ++b) {
    band[(((size_t)(part * NB + b)) * ND + d0) * NYY + tid] = acc[2*b];   // coalesced
    if (!single)
      band[(((size_t)(part * NB + b)) * ND + (ND - dg)) * NYY + tid] = acc[2*b+1];
  }
}

// ---------------- kernel 4b: bandS[b][d][y] = sum_part band[part][b][d][y] ----------------
__global__ __launch_bounds__(256) void fk_sum(const float2* __restrict__ band,
                                              float2* __restrict__ bandS, int nparts) {
  const int n = blockIdx.x * 256 + threadIdx.x;   // [b][d][y]: coalesced read AND write
  float2 s = make_float2(0.f, 0.f);
  for (int p = 0; p < nparts; ++p) {
    float2 v = band[(size_t)p * (NB * ND * NYY) + n];
    s.x += v.x; s.y += v.y;
  }
  bandS[n] = s;
}

// ---------------- kernel 5: lateral transform as 256-pt inverse FFT + magnitude ----
// img[x] = sum_m S[m] e^{+i 2pi m x/256}, S[md]=band[d], md = d<64 ? d : d+128.
__global__ __launch_bounds__(256) void fk_img(const float2* __restrict__ bandS,
                                              const float* __restrict__ scale,
                                              float* __restrict__ out, float inv_norm) {
  const int y = blockIdx.x;
  const int b = blockIdx.y;
  const int tid = threadIdx.x;
  __shared__ float2 A[256];
  __shared__ float2 Bb[256];
  {
    float2 v = make_float2(0.f, 0.f);
    if (tid < 64)        v = bandS[((size_t)(b * ND + tid)) * NYY + y];        // bin d
    else if (tid >= 192) v = bandS[((size_t)(b * ND + tid - 128)) * NYY + y];  // bin d+128
    A[tid] = v;
  }
  __syncthreads();
  float2* src = A;
  float2* dst = Bb;
  for (int p = 1; p <= 128; p <<= 1) {
    if (tid < 128) {
      int i = tid;
      int k = i & (p - 1);
      float2 u = src[i];
      float2 v = src[i + 128];
      float ang = 3.14159265358979323846f * ((float)k / (float)p);   // +: inverse
      float sn, cs; __sincosf(ang, &sn, &cs);
      float2 vw = make_float2(v.x * cs - v.y * sn, v.x * sn + v.y * cs);
      int j = ((i - k) << 1) + k;
      dst[j]     = make_float2(u.x + vw.x, u.y + vw.y);
      dst[j + p] = make_float2(u.x - vw.x, u.y - vw.y);
    }
    __syncthreads();
    float2* t = src; src = dst; dst = t;
  }
  float2 r = src[tid];
  float mag = sqrtf(r.x * r.x + r.y * r.y);
  out[((size_t)b * NYY + y) * NXX + tid] = mag * scale[b] * inv_norm;
}

extern "C" void kernel_launch(void* const* d_in, const int* in_sizes, int n_in,
                              void* d_out, int out_size, void* d_ws, size_t ws_size,
                              hipStream_t stream) {
  const float* sino = (const float*)d_in[0];
  float* out = (float*)d_out;
  char* ws = (char*)d_ws;

  float*   scale = (float*)(ws + 0);
  double2* part  = (double2*)(ws + PART_OFF);
  float2*  specT = (float2*)(ws + SPECT_OFF);
  float2*  sf    = (float2*)(ws + SF_OFF);
  float2*  band  = (float2*)(ws + BAND_OFF);

  // pick f-partition count from available workspace (deterministic given ws_size)
  int FPART = 4;
  if (ws_size >= (size_t)BAND_OFF + 17u * BAND_PART_BYTES) FPART = 16;
  else if (ws_size >= (size_t)BAND_OFF + 9u * BAND_PART_BYTES) FPART = 8;
  const int flen_base = (NF + FPART - 1) / FPART;          // 65 / 129 / 257
  float2* bandS = (float2*)(ws + BAND_OFF + (size_t)FPART * BAND_PART_BYTES);

  double apod_sum = 0.0;
  for (int n = 0; n < ND; ++n) apod_sum += 0.5 - 0.5 * cos(6.283185307179586 * (double)n / 127.0);
  const float inv_norm = (float)(1.0 / (apod_sum * 2048.0));

  fk_part_sums<<<dim3(32, NB), 256, 0, stream>>>(sino, part);
  fk_scale_k <<<1, 64, 0, stream>>>(part, scale);
  fk_tfft    <<<NB * ND, 256, 0, stream>>>(sino, specT);
  fk_dfft    <<<dim3((NF + 3) / 4, NB), 256, 0, stream>>>(specT, sf);
  fk_band    <<<dim3(65, FPART), 256, 0, stream>>>(sf, band, flen_base);
  fk_sum     <<<NB * ND * NYY / 256, 256, 0, stream>>>(band, bandS, FPART);
  fk_img     <<<dim3(NYY, NB), 256, 0, stream>>>(bandS, scale, out, inv_norm);
}

// Round 7
// 92.329 us; speedup vs baseline: 1.1877x; 1.0014x over previous
//
#include <hip/hip_runtime.h>
#include <math.h>

#define NB 8
#define ND 128
#define NT 2048
#define NF 1025
#define NYY 256
#define NXX 256

#define SPEC_BYTES 8396800          /* 8*128*1025*8 */
#define BAND_PART_BYTES 2097152     /* 8*128*256*8 */
#define PART_OFF   1024
#define SPECT_OFF  8192
#define SF_OFF     (SPECT_OFF + SPEC_BYTES)            /* 8,404,992 */
#define BAND_OFF   (SF_OFF + SPEC_BYTES)               /* 16,801,792 */
// bandS goes after band (FPART * BAND_PART_BYTES). No aliasing at all.

// ---------------- kernel 1a: per-chunk sums for standardization ----------------
__global__ __launch_bounds__(256) void fk_part_sums(const float* __restrict__ sino,
                                                    double2* __restrict__ part) {
  const int c = blockIdx.x;   // 0..31 chunk
  const int b = blockIdx.y;   // 0..7 batch
  const int tid = threadIdx.x;
  const int chunk = ND * NT / 32;  // 8192
  const float* p = sino + (size_t)b * ND * NT + (size_t)c * chunk;
  double s = 0.0, ss = 0.0;
  for (int i = tid; i < chunk; i += 256) {
    float v = p[i];
    s += (double)v;
    ss += (double)v * (double)v;
  }
  __shared__ double shs[256];
  __shared__ double shq[256];
  shs[tid] = s; shq[tid] = ss;
  __syncthreads();
  for (int o = 128; o > 0; o >>= 1) {
    if (tid < o) { shs[tid] += shs[tid + o]; shq[tid] += shq[tid + o]; }
    __syncthreads();
  }
  if (tid == 0) part[b * 32 + c] = make_double2(shs[0], shq[0]);
}

// ---------------- kernel 1b: finalize 1/sqrt(var+eps) ----------------
__global__ void fk_scale_k(const double2* __restrict__ part, float* __restrict__ scale) {
  int t = threadIdx.x;
  if (t < NB) {
    double s = 0.0, ss = 0.0;
    for (int c = 0; c < 32; ++c) { double2 v = part[t * 32 + c]; s += v.x; ss += v.y; }
    const double n = (double)(ND * NT);
    double mean = s / n;
    double var = ss / n - mean * mean;
    scale[t] = (float)(1.0 / sqrt(var + 1.1920928955078125e-7));
  }
}

// ---------------- kernel 2: real 2048-pt rfft via 1024-pt complex FFT + untangle ----
__global__ __launch_bounds__(256) void fk_tfft(const float* __restrict__ sino,
                                               float2* __restrict__ specT) {
  const int row = blockIdx.x;      // b*ND + d
  const int d = row & (ND - 1);
  const int tid = threadIdx.x;
  __shared__ float2 bufA[1024];
  __shared__ float2 bufB[1024];
  const float ap = (float)(0.5 - 0.5 * cos(6.283185307179586 * (double)d / 127.0));
  const float2* in = (const float2*)(sino + (size_t)row * NT);   // z[n] = x[2n] + i x[2n+1]
  for (int i = tid; i < 1024; i += 256) {
    float2 v = in[i];
    bufA[i] = make_float2(v.x * ap, v.y * ap);
  }
  __syncthreads();
  float2* src = bufA;
  float2* dst = bufB;
  for (int p = 1; p <= 512; p <<= 1) {
    #pragma unroll
    for (int it = 0; it < 2; ++it) {
      int i = tid + it * 256;
      int k = i & (p - 1);
      float2 u = src[i];
      float2 v = src[i + 512];
      float ang = -3.14159265358979323846f * ((float)k / (float)p);
      float sn, cs; __sincosf(ang, &sn, &cs);
      float2 vw = make_float2(v.x * cs - v.y * sn, v.x * sn + v.y * cs);
      int j = ((i - k) << 1) + k;
      dst[j]     = make_float2(u.x + vw.x, u.y + vw.y);
      dst[j + p] = make_float2(u.x - vw.x, u.y - vw.y);
    }
    __syncthreads();
    float2* t = src; src = dst; dst = t;
  }
  // src = Z[0..1023]; untangle to rfft X[0..1024]
  float2* out = specT + (size_t)row * NF;
  for (int k = tid; k < 1024; k += 256) {
    float2 zk = src[k];
    float2 zc = src[(1024 - k) & 1023]; zc.y = -zc.y;          // conj
    float2 xe = make_float2(0.5f * (zk.x + zc.x), 0.5f * (zk.y + zc.y));
    float ax = zk.x - zc.x, ay = zk.y - zc.y;
    float2 xo = make_float2(0.5f * ay, -0.5f * ax);            // (Z - Zc)/(2i)
    float ang = -3.14159265358979323846f * ((float)k / 1024.0f);
    float sn, cs; __sincosf(ang, &sn, &cs);
    out[k] = make_float2(xe.x + cs * xo.x - sn * xo.y,
                         xe.y + cs * xo.y + sn * xo.x);
  }
  if (tid == 0) {
    float2 z0 = src[0];
    out[1024] = make_float2(z0.x - z0.y, 0.0f);
  }
}

// ---------------- kernel 3: detector FFT (128-pt) + prop_mask*fw ----------------
__global__ __launch_bounds__(256) void fk_dfft(const float2* __restrict__ specT,
                                               float2* __restrict__ sf) {
  const int b = blockIdx.y;
  const int f0 = blockIdx.x * 4;
  const int sub = threadIdx.x >> 6;   // 0..3 (which f)
  const int i = threadIdx.x & 63;     // butterfly index
  const int f = f0 + sub;
  const bool valid = (f < NF);
  __shared__ float2 A[4][128];
  __shared__ float2 Bf[4][128];
  if (valid) {
    const float2* col = specT + ((size_t)b * ND) * NF + f;
    A[sub][i]      = col[(size_t)i * NF];
    A[sub][i + 64] = col[(size_t)(i + 64) * NF];
  }
  __syncthreads();
  float2 (*src)[128] = A;
  float2 (*dst)[128] = Bf;
  for (int p = 1; p <= 64; p <<= 1) {
    if (valid) {
      int k = i & (p - 1);
      float2 u = src[sub][i];
      float2 v = src[sub][i + 64];
      float ang = -3.14159265358979323846f * ((float)k / (float)p);
      float sn, cs; __sincosf(ang, &sn, &cs);
      float2 vw = make_float2(v.x * cs - v.y * sn, v.x * sn + v.y * cs);
      int j = ((i - k) << 1) + k;
      dst[sub][j]     = make_float2(u.x + vw.x, u.y + vw.y);
      dst[sub][j + p] = make_float2(u.x - vw.x, u.y - vw.y);
    }
    __syncthreads();
    float2 (*t)[128] = src; src = dst; dst = t;
  }
  if (valid) {
    const float fwv = (f == 0 || f == NF - 1) ? 1.0f : 2.0f;
    double freqd = (double)f / 5.12e-5;
    float omega = (float)(freqd * 6.283185307179586);
    float woc = omega / 1540.0f;
    float woc2 = __fmul_rn(woc, woc);
    #pragma unroll
    for (int h = 0; h < 2; ++h) {
      int kd = i + h * 64;
      int kt = kd < 64 ? kd : kd - 128;
      float kxv = (float)(6.283185307179586 * ((double)kt / 0.0384));
      float kzsq = __fsub_rn(woc2, __fmul_rn(kxv, kxv));
      float m = (kzsq > 0.0f) ? fwv : 0.0f;
      float2 v = src[sub][kd];
      sf[((size_t)(b * ND + kd)) * NF + f] = make_float2(v.x * m, v.y * m);
    }
  }
}

// ---------------- kernel 4: band[part][b][d][y] = sum_f sf[b,d,f]*exp(i*kz*y) ----------------
// Full f-range staged in LDS (conflict-free); unroll-4 macro-iterations:
// one float4 kz read + 4 sincos + 32 broadcast b128 reads + 256 FMA.
__global__ __launch_bounds__(256) void fk_band(const float2* __restrict__ sf,
                                               float2* __restrict__ band,
                                               int flen_base) {
  const int dg   = blockIdx.x;       // 0..64
  const int part = blockIdx.y;       // 0..FPART-1
  const int f0 = part * flen_base;
  const int flen = min(flen_base, NF - f0);
  const int tid = threadIdx.x;       // y
  const int d0 = dg;
  const bool single = (dg == 0) || (dg == 64);
  const int d1 = single ? dg : (ND - dg);    // always a valid row
  const int fpad = (flen_base + 3) & ~3;     // 68 (FPART=16) or 132 (FPART=8)

  __shared__ float4 sfs[8][132];             // [pair j = batch][ff] : {reA,imA,reB,imB}
  __shared__ float4 kzs4[33];
  float* kzs = (float*)kzs4;

  const size_t bstr = (size_t)ND * NF;
  const float2* baseA = sf + (size_t)d0 * NF + f0;
  const float2* baseB = sf + (size_t)d1 * NF + f0;
  if (tid < fpad) {
    const int ff = tid;
    #pragma unroll
    for (int j = 0; j < 8; ++j) {
      float4 v = make_float4(0.f, 0.f, 0.f, 0.f);
      if (ff < flen) {
        float2 a = baseA[(size_t)j * bstr + ff];
        float2 b = baseB[(size_t)j * bstr + ff];
        v = make_float4(a.x, a.y, b.x, b.y);
      }
      sfs[j][ff] = v;
    }
    float kzv = 0.0f;
    if (ff < flen) {
      int f = f0 + ff;
      float kxv = (float)(6.283185307179586 * ((double)d0 / 0.0384));
      float kx2 = __fmul_rn(kxv, kxv);
      double freqd = (double)f / 5.12e-5;
      float omega = (float)(freqd * 6.283185307179586);
      float woc = omega / 1540.0f;
      float kzsq = __fsub_rn(__fmul_rn(woc, woc), kx2);
      kzv = (kzsq > 0.0f) ? sqrtf(kzsq) : 0.0f;
    }
    kzs[ff] = kzv;
  }
  __syncthreads();

  const float yv = (float)(1.0e-3 + (double)tid * 1.5e-4);
  float2 acc[16];
  #pragma unroll
  for (int r = 0; r < 16; ++r) acc[r] = make_float2(0.f, 0.f);

  const int nmac = fpad >> 2;
  for (int m = 0; m < nmac; ++m) {
    float4 k4 = kzs4[m];
    float sn0, cs0, sn1, cs1, sn2, cs2, sn3, cs3;
    __sincosf(k4.x * yv, &sn0, &cs0);
    __sincosf(k4.y * yv, &sn1, &cs1);
    __sincosf(k4.z * yv, &sn2, &cs2);
    __sincosf(k4.w * yv, &sn3, &cs3);
    const int ffb = m << 2;
    #pragma unroll
    for (int u = 0; u < 4; ++u) {
      const float cs = (u == 0) ? cs0 : (u == 1) ? cs1 : (u == 2) ? cs2 : cs3;
      const float sn = (u == 0) ? sn0 : (u == 1) ? sn1 : (u == 2) ? sn2 : sn3;
      #pragma unroll
      for (int j = 0; j < 8; ++j) {
        float4 p = sfs[j][ffb + u];          // uniform -> LDS broadcast, conflict-free
        acc[2*j].x   = fmaf(p.x, cs, fmaf(-p.y, sn, acc[2*j].x));
        acc[2*j].y   = fmaf(p.x, sn, fmaf( p.y, cs, acc[2*j].y));
        acc[2*j+1].x = fmaf(p.z, cs, fmaf(-p.w, sn, acc[2*j+1].x));
        acc[2*j+1].y = fmaf(p.z, sn, fmaf( p.w, cs, acc[2*j+1].y));
      }
    }
  }

  #pragma unroll
  for (int b = 0; b < NB; ++b) {
    band[(((size_t)(part * NB + b)) * ND + d0) * NYY + tid] = acc[2*b];   // coalesced
    if (!single)
      band[(((size_t)(part * NB + b)) * ND + (ND - dg)) * NYY + tid] = acc[2*b+1];
  }
}

// ---------------- kernel 4b: bandS[b][d][y] = sum_part band[part][b][d][y] ----------------
__global__ __launch_bounds__(256) void fk_sum(const float2* __restrict__ band,
                                              float2* __restrict__ bandS, int nparts) {
  const int n = blockIdx.x * 256 + threadIdx.x;   // [b][d][y]: coalesced read AND write
  float2 s = make_float2(0.f, 0.f);
  for (int p = 0; p < nparts; ++p) {
    float2 v = band[(size_t)p * (NB * ND * NYY) + n];
    s.x += v.x; s.y += v.y;
  }
  bandS[n] = s;
}

// ---------------- kernel 5: lateral transform as 256-pt inverse FFT + magnitude ----
// img[x] = sum_m S[m] e^{+i 2pi m x/256}, S[md]=band[d], md = d<64 ? d : d+128.
__global__ __launch_bounds__(256) void fk_img(const float2* __restrict__ bandS,
                                              const float* __restrict__ scale,
                                              float* __restrict__ out, float inv_norm) {
  const int y = blockIdx.x;
  const int b = blockIdx.y;
  const int tid = threadIdx.x;
  __shared__ float2 A[256];
  __shared__ float2 Bb[256];
  {
    float2 v = make_float2(0.f, 0.f);
    if (tid < 64)        v = bandS[((size_t)(b * ND + tid)) * NYY + y];        // bin d
    else if (tid >= 192) v = bandS[((size_t)(b * ND + tid - 128)) * NYY + y];  // bin d+128
    A[tid] = v;
  }
  __syncthreads();
  float2* src = A;
  float2* dst = Bb;
  for (int p = 1; p <= 128; p <<= 1) {
    if (tid < 128) {
      int i = tid;
      int k = i & (p - 1);
      float2 u = src[i];
      float2 v = src[i + 128];
      float ang = 3.14159265358979323846f * ((float)k / (float)p);   // +: inverse
      float sn, cs; __sincosf(ang, &sn, &cs);
      float2 vw = make_float2(v.x * cs - v.y * sn, v.x * sn + v.y * cs);
      int j = ((i - k) << 1) + k;
      dst[j]     = make_float2(u.x + vw.x, u.y + vw.y);
      dst[j + p] = make_float2(u.x - vw.x, u.y - vw.y);
    }
    __syncthreads();
    float2* t = src; src = dst; dst = t;
  }
  float2 r = src[tid];
  float mag = sqrtf(r.x * r.x + r.y * r.y);
  out[((size_t)b * NYY + y) * NXX + tid] = mag * scale[b] * inv_norm;
}

extern "C" void kernel_launch(void* const* d_in, const int* in_sizes, int n_in,
                              void* d_out, int out_size, void* d_ws, size_t ws_size,
                              hipStream_t stream) {
  const float* sino = (const float*)d_in[0];
  float* out = (float*)d_out;
  char* ws = (char*)d_ws;

  float*   scale = (float*)(ws + 0);
  double2* part  = (double2*)(ws + PART_OFF);
  float2*  specT = (float2*)(ws + SPECT_OFF);
  float2*  sf    = (float2*)(ws + SF_OFF);
  float2*  band  = (float2*)(ws + BAND_OFF);

  // pick f-partition count from available workspace (deterministic given ws_size)
  int FPART = 8;
  if (ws_size >= (size_t)BAND_OFF + 17u * BAND_PART_BYTES) FPART = 16;
  const int flen_base = (NF + FPART - 1) / FPART;          // 65 / 129
  float2* bandS = (float2*)(ws + BAND_OFF + (size_t)FPART * BAND_PART_BYTES);

  double apod_sum = 0.0;
  for (int n = 0; n < ND; ++n) apod_sum += 0.5 - 0.5 * cos(6.283185307179586 * (double)n / 127.0);
  const float inv_norm = (float)(1.0 / (apod_sum * 2048.0));

  fk_part_sums<<<dim3(32, NB), 256, 0, stream>>>(sino, part);
  fk_scale_k <<<1, 64, 0, stream>>>(part, scale);
  fk_tfft    <<<NB * ND, 256, 0, stream>>>(sino, specT);
  fk_dfft    <<<dim3((NF + 3) / 4, NB), 256, 0, stream>>>(specT, sf);
  fk_band    <<<dim3(65, FPART), 256, 0, stream>>>(sf, band, flen_base);
  fk_sum     <<<NB * ND * NYY / 256, 256, 0, stream>>>(band, bandS, FPART);
  fk_img     <<<dim3(NYY, NB), 256, 0, stream>>>(bandS, scale, out, inv_norm);
}